// Round 5
// baseline (1119.036 us; speedup 1.0000x reference)
//
#include <hip/hip_runtime.h>
#include <math.h>

#define NR 5
#define NB 7
#define NS 119
#define NA 25000
#define NE 1000000
#define OC 360           // output columns per atom
#define MUS 100          // unique moment floats per atom
#define CHUNK 64         // atoms per bucket / contract block
#define NBK 391          // ceil(NA/CHUNK)
#define BCAP 3072        // records per bucket (lambda~2500, +10 sigma)
#define MPAD 101         // LDS stride: gcd(101 mod 32 = 5, 32) = 1 -> conflict-free
#define CAPI 112         // fallback id-bin capacity

// tril index tables (wave-uniform index -> scalar loads)
static constexpr int T2I[15] = {0,1,1,2,2,2,3,3,3,3,4,4,4,4,4};
static constexpr int T2J[15] = {0,0,1,0,1,2,0,1,2,3,0,1,2,3,4};
static constexpr int T3I[35] = {0,1,1,1,2,2,2,2,2,2,3,3,3,3,3,3,3,3,3,3,4,4,4,4,4,4,4,4,4,4,4,4,4,4,4};
static constexpr int T3J[35] = {0,0,1,1,0,1,1,2,2,2,0,1,1,2,2,2,3,3,3,3,0,1,1,2,2,2,3,3,3,3,4,4,4,4,4};
static constexpr int T3K[35] = {0,0,0,1,0,0,1,0,1,2,0,0,1,0,1,2,0,1,2,3,0,0,1,0,1,2,0,1,2,3,0,1,2,3,4};

static constexpr int P2[9]  = {0,1,2, 1,3,4, 2,4,5};
static constexpr int P3[27] = {0,1,4, 1,2,5, 4,5,7,
                               1,2,5, 2,3,6, 5,6,8,
                               4,5,7, 5,6,8, 7,8,9};
static constexpr float W2[6]  = {1.f,2.f,2.f,1.f,2.f,1.f};
static constexpr float W3[10] = {1.f,3.f,3.f,1.f,3.f,6.f,3.f,3.f,3.f,1.f};

// ============================ FAST PATH ==================================
// pass 1: fused edge compute + bucket-append record scatter.
// Buckets = 64-atom ranges -> 391 moving tails -> writes cluster/merge.
__global__ __launch_bounds__(256) void edge_record_kernel(
    const float* __restrict__ dr_vec, const int* __restrict__ Z,
    const int* __restrict__ nbr, const float* __restrict__ coeffs,
    int* __restrict__ cursor, float* __restrict__ rec,
    unsigned char* __restrict__ meta)
{
    int e = blockIdx.x * 256 + threadIdx.x;
    if (e >= NE) return;
    float x = dr_vec[3*e+0], y = dr_vec[3*e+1], z = dr_vec[3*e+2];
    int ai = nbr[e];
    int aj = nbr[NE + e];

    float dr = sqrtf(x*x + y*y + z*z);
    if (dr >= 6.0f) return;                 // cutoff==0 -> zero contribution
    int Zi = Z[ai], Zj = Z[aj];

    float inv = 1.0f / (dr + 1e-5f);
    float d0 = x*inv, d1 = y*inv, d2 = z*inv;

    const float PI_F = 3.14159265358979323846f;
    const float betta = 49.0f / 36.0f;
    float rad_norm = powf(2.0f * betta / PI_F, 0.75f);
    float cut = 0.5f*(cosf(PI_F * dr * (1.0f/6.0f)) + 1.0f);
    float scale = cut * 0.3779644730092272272f;   // 1/sqrt(7)

    float basis[NB];
#pragma unroll
    for (int b = 0; b < NB; b++) {
        float t = dr - (float)b;
        basis[b] = rad_norm * expf(-betta * t * t);
    }

    const float* cp = coeffs + ((size_t)(Zi*NS + Zj)) * (NR*NB);
    float rad[NR];
#pragma unroll
    for (int r = 0; r < NR; r++) {
        float s = 0.f;
#pragma unroll
        for (int b = 0; b < NB; b++) s += basis[b] * cp[r*NB + b];
        rad[r] = s * scale;
    }

    int bkt = aj >> 6;
    int pos = __hip_atomic_fetch_add(&cursor[bkt], 1, __ATOMIC_RELAXED, __HIP_MEMORY_SCOPE_AGENT);
    if (pos < BCAP) {
        size_t idx = (size_t)bkt * BCAP + pos;
        float4* rp = (float4*)(rec + idx * 8);
        rp[0] = make_float4(rad[0], rad[1], rad[2], rad[3]);
        rp[1] = make_float4(rad[4], d0, d1, d2);
        meta[idx] = (unsigned char)(aj & 63);
    }
}

// pass 2: per-bucket block: coalesced record stream -> LDS-atomic moment
// tile -> in-place contraction (Mu never touches HBM).
__global__ __launch_bounds__(256) void accum_contract_kernel(
    const int* __restrict__ cursor, const float* __restrict__ rec,
    const unsigned char* __restrict__ meta, float* __restrict__ out)
{
    __shared__ float lds[CHUNK * MPAD];
    int bkt  = blockIdx.x;
    int base = bkt * CHUNK;
    int nat  = min(CHUNK, NA - base);

    for (int i = threadIdx.x; i < CHUNK * MPAD; i += 256) lds[i] = 0.f;
    __syncthreads();

    int n = min(cursor[bkt], BCAP);
    for (int p = threadIdx.x; p < n; p += 256) {
        size_t idx = (size_t)bkt * BCAP + p;
        const float4* rp = (const float4*)(rec + idx * 8);
        float4 r0 = rp[0], r1 = rp[1];
        int laj = meta[idx];
        float* t = &lds[laj * MPAD];

        float rad[NR] = {r0.x, r0.y, r0.z, r0.w, r1.x};
        float d0 = r1.y, d1 = r1.z, d2 = r1.w;
        float q2[6] = {d0*d0, d1*d0, d2*d0, d1*d1, d2*d1, d2*d2};
        float q3[10] = {d0*q2[0], d1*q2[0], d0*q2[3], d1*q2[3], d2*q2[0],
                        d2*q2[1], d2*q2[3], d0*q2[5], d1*q2[5], d2*q2[5]};

#pragma unroll
        for (int r = 0; r < NR; r++) {
            float rv = rad[r];
            atomicAdd(&t[r], rv);
            atomicAdd(&t[5 + r*3 + 0], rv*d0);
            atomicAdd(&t[5 + r*3 + 1], rv*d1);
            atomicAdd(&t[5 + r*3 + 2], rv*d2);
#pragma unroll
            for (int q = 0; q < 6; q++)  atomicAdd(&t[20 + r*6  + q], rv*q2[q]);
#pragma unroll
            for (int q = 0; q < 10; q++) atomicAdd(&t[50 + r*10 + q], rv*q3[q]);
        }
    }
    __syncthreads();

    // ---- contract phase: lanes = atoms, waves split the 360 columns ----
    int wave = threadIdx.x >> 6, lane = threadIdx.x & 63;
    int a2 = base + lane;
    bool valid = (lane < nat);
    int mb = lane * MPAD;

#define ML(o) lds[mb + (o)]

    for (int cc = wave; cc < 360; cc += 4) {
        if (!valid) continue;
        float v; int dest;

        if (cc < 5) {
            v = ML(cc);
            dest = a2 * OC + cc;
        } else if (cc < 20) {
            int l = cc - 5;
            int r = T2I[l], s = T2J[l];
            float acc2 = 0.f;
#pragma unroll
            for (int i = 0; i < 3; i++) acc2 += ML(5 + r*3 + i) * ML(5 + s*3 + i);
            v = acc2;
            int f = l * NA + a2; int aa = f / 15; dest = aa * OC + 5 + (f - aa*15);
        } else if (cc < 35) {
            int l = cc - 20;
            int r = T2I[l], s = T2J[l];
            float acc2 = 0.f;
#pragma unroll
            for (int p = 0; p < 6; p++) acc2 += W2[p] * ML(20 + r*6 + p) * ML(20 + s*6 + p);
            v = acc2;
            int f = l * NA + a2; int aa = f / 15; dest = aa * OC + 20 + (f - aa*15);
        } else if (cc < 50) {
            int l = cc - 35;
            int r = T2I[l], s = T2J[l];
            float acc2 = 0.f;
#pragma unroll
            for (int p = 0; p < 10; p++) acc2 += W3[p] * ML(50 + r*10 + p) * ML(50 + s*10 + p);
            v = acc2;
            int f = l * NA + a2; int aa = f / 15; dest = aa * OC + 35 + (f - aa*15);
        } else if (cc < 85) {
            int l = cc - 50;
            int r = T3I[l], s = T3J[l], t = T3K[l];
            float R[6], S[6], T[6];
#pragma unroll
            for (int p = 0; p < 6; p++) { R[p]=ML(20+r*6+p); S[p]=ML(20+s*6+p); T[p]=ML(20+t*6+p); }
            float acc2 = 0.f;
#pragma unroll
            for (int i = 0; i < 3; i++)
#pragma unroll
            for (int j = 0; j < 3; j++)
#pragma unroll
            for (int k = 0; k < 3; k++)
                acc2 += R[P2[i*3+j]] * S[P2[i*3+k]] * T[P2[j*3+k]];
            v = acc2;
            int f = l * NA + a2; int aa = f / 35; dest = aa * OC + 50 + (f - aa*35);
        } else if (cc < 160) {
            int l = cc - 85;
            int p = l / 5, t = l - p*5;
            int r = T2I[p], s = T2J[p];
            float T[6];
#pragma unroll
            for (int q = 0; q < 6; q++) T[q] = ML(20 + t*6 + q);
            float acc2 = 0.f;
#pragma unroll
            for (int i = 0; i < 3; i++)
#pragma unroll
            for (int j = 0; j < 3; j++)
                acc2 += ML(5 + r*3 + i) * ML(5 + s*3 + j) * T[P2[i*3+j]];
            v = acc2;
            int f = l * NA + a2; int aa = f / 75; dest = aa * OC + 85 + (f - aa*75);
        } else if (cc < 235) {
            int l = cc - 160;
            int p = l / 5, t = l - p*5;
            int r = T2I[p], s = T2J[p];
            float R[10], S[10], T[6];
#pragma unroll
            for (int q = 0; q < 10; q++) { R[q]=ML(50+r*10+q); S[q]=ML(50+s*10+q); }
#pragma unroll
            for (int q = 0; q < 6;  q++) T[q] = ML(20 + t*6 + q);
            float acc2 = 0.f;
#pragma unroll
            for (int k = 0; k < 3; k++)
#pragma unroll
            for (int l2 = 0; l2 < 3; l2++) {
                float inner = 0.f;
#pragma unroll
                for (int i = 0; i < 3; i++)
#pragma unroll
                for (int j = 0; j < 3; j++)
                    inner += R[P3[(i*3+j)*3+k]] * S[P3[(i*3+j)*3+l2]];
                acc2 += inner * T[P2[k*3+l2]];
            }
            v = acc2;
            int f = l * NA + a2; int aa = f / 75; dest = aa * OC + 160 + (f - aa*75);
        } else {
            int l = cc - 235;
            int r = l / 25; int rem = l - r*25; int s = rem / 5; int t = rem - s*5;
            float R[10], S[6], T1[3];
#pragma unroll
            for (int q = 0; q < 10; q++) R[q] = ML(50 + r*10 + q);
#pragma unroll
            for (int q = 0; q < 6;  q++) S[q] = ML(20 + s*6 + q);
#pragma unroll
            for (int q = 0; q < 3;  q++) T1[q] = ML(5 + t*3 + q);
            float acc2 = 0.f;
#pragma unroll
            for (int i = 0; i < 3; i++)
#pragma unroll
            for (int j = 0; j < 3; j++)
#pragma unroll
            for (int k = 0; k < 3; k++)
                acc2 += R[P3[(i*3+j)*3+k]] * S[P2[i*3+j]] * T1[k];
            v = acc2;
            int f = l * NA + a2; int aa = f / 125; dest = aa * OC + 235 + (f - aa*125);
        }
        out[dest] = v;
    }
#undef ML
}

// ========================= FALLBACK PATH (round 3) =======================
__global__ __launch_bounds__(256) void scatter_kernel(
    const int* __restrict__ nbr, int* __restrict__ cursor, int* __restrict__ bins)
{
    int e = blockIdx.x * 256 + threadIdx.x;
    if (e >= NE) return;
    int aj = nbr[NE + e];
    int pos = __hip_atomic_fetch_add(&cursor[aj], 1, __ATOMIC_RELAXED, __HIP_MEMORY_SCOPE_AGENT);
    if (pos < CAPI) bins[(size_t)aj * CAPI + pos] = e;
}

__global__ __launch_bounds__(256) void accum_kernel(
    const float* __restrict__ dr_vec, const int* __restrict__ Z,
    const int* __restrict__ nbr, const float* __restrict__ coeffs,
    const int* __restrict__ cursor, const int* __restrict__ bins,
    float* __restrict__ Mu)
{
    __shared__ float red[32 * MUS];
    int t   = blockIdx.x * 256 + threadIdx.x;
    int a   = t >> 3;
    int sub = t & 7;
    int al  = threadIdx.x >> 3;
    int n   = (a < NA) ? min(cursor[a], CAPI) : 0;
    int Zj  = (a < NA) ? Z[a] : 0;

    float acc[MUS];
#pragma unroll
    for (int i = 0; i < MUS; i++) acc[i] = 0.f;

    const int* mybin = bins + (size_t)a * CAPI;
    const float PI_F = 3.14159265358979323846f;
    const float betta = 49.0f / 36.0f;
    float rad_norm = powf(2.0f * betta / PI_F, 0.75f);

    for (int p = sub; p < n; p += 8) {
        int e = mybin[p];
        float x = dr_vec[3*e+0], y = dr_vec[3*e+1], z = dr_vec[3*e+2];
        int Zi = Z[nbr[e]];

        float dr  = sqrtf(x*x + y*y + z*z);
        float inv = 1.0f / (dr + 1e-5f);
        float d0 = x*inv, d1 = y*inv, d2 = z*inv;

        float cut = (dr < 6.0f) ? 0.5f*(cosf(PI_F * dr * (1.0f/6.0f)) + 1.0f) : 0.0f;
        float scale = cut * 0.3779644730092272272f;

        float basis[NB];
#pragma unroll
        for (int b = 0; b < NB; b++) {
            float tt = dr - (float)b;
            basis[b] = rad_norm * expf(-betta * tt * tt);
        }

        const float* cp = coeffs + ((size_t)(Zi*NS + Zj)) * (NR*NB);
        float rad[NR];
#pragma unroll
        for (int r = 0; r < NR; r++) {
            float s = 0.f;
#pragma unroll
            for (int b = 0; b < NB; b++) s += basis[b] * cp[r*NB + b];
            rad[r] = s * scale;
        }

        float q2[6] = {d0*d0, d1*d0, d2*d0, d1*d1, d2*d1, d2*d2};
        float q3[10] = {d0*q2[0], d1*q2[0], d0*q2[3], d1*q2[3], d2*q2[0],
                        d2*q2[1], d2*q2[3], d0*q2[5], d1*q2[5], d2*q2[5]};

#pragma unroll
        for (int r = 0; r < NR; r++) {
            float rv = rad[r];
            acc[r] += rv;
            acc[5 + r*3 + 0] += rv*d0;
            acc[5 + r*3 + 1] += rv*d1;
            acc[5 + r*3 + 2] += rv*d2;
#pragma unroll
            for (int q = 0; q < 6; q++)  acc[20 + r*6  + q] += rv*q2[q];
#pragma unroll
            for (int q = 0; q < 10; q++) acc[50 + r*10 + q] += rv*q3[q];
        }
    }

#pragma unroll
    for (int i = 0; i < MUS; i++) {
        float v = acc[i];
        v += __shfl_xor(v, 1, 64);
        v += __shfl_xor(v, 2, 64);
        v += __shfl_xor(v, 4, 64);
        if (sub == 0) red[al * MUS + i] = v;
    }
    __syncthreads();

    for (int u = threadIdx.x; u < 32 * MUS; u += 256) {
        int ga = blockIdx.x * 32 + u / MUS;
        if (ga < NA) Mu[(size_t)ga * MUS + (u - (u / MUS) * MUS)] = red[u];
    }
}

__global__ __launch_bounds__(256) void contract_kernel(
    const float* __restrict__ Mu, float* __restrict__ out)
{
    __shared__ float lds[CHUNK * MPAD];
    int base = blockIdx.x * CHUNK;
    int nat  = min(CHUNK, NA - base);

    for (int t = threadIdx.x; t < nat * MUS; t += 256) {
        int al = t / MUS, off = t - al * MUS;
        lds[al * MPAD + off] = Mu[(size_t)base * MUS + t];
    }
    __syncthreads();

    int wave = threadIdx.x >> 6, lane = threadIdx.x & 63;
    int a2 = base + lane;
    bool valid = (lane < nat);
    int mb = lane * MPAD;

#define ML(o) lds[mb + (o)]

    for (int cc = wave; cc < 360; cc += 4) {
        if (!valid) continue;
        float v; int dest;

        if (cc < 5) {
            v = ML(cc);
            dest = a2 * OC + cc;
        } else if (cc < 20) {
            int l = cc - 5;
            int r = T2I[l], s = T2J[l];
            float acc = 0.f;
#pragma unroll
            for (int i = 0; i < 3; i++) acc += ML(5 + r*3 + i) * ML(5 + s*3 + i);
            v = acc;
            int f = l * NA + a2; int aa = f / 15; dest = aa * OC + 5 + (f - aa*15);
        } else if (cc < 35) {
            int l = cc - 20;
            int r = T2I[l], s = T2J[l];
            float acc = 0.f;
#pragma unroll
            for (int p = 0; p < 6; p++) acc += W2[p] * ML(20 + r*6 + p) * ML(20 + s*6 + p);
            v = acc;
            int f = l * NA + a2; int aa = f / 15; dest = aa * OC + 20 + (f - aa*15);
        } else if (cc < 50) {
            int l = cc - 35;
            int r = T2I[l], s = T2J[l];
            float acc = 0.f;
#pragma unroll
            for (int p = 0; p < 10; p++) acc += W3[p] * ML(50 + r*10 + p) * ML(50 + s*10 + p);
            v = acc;
            int f = l * NA + a2; int aa = f / 15; dest = aa * OC + 35 + (f - aa*15);
        } else if (cc < 85) {
            int l = cc - 50;
            int r = T3I[l], s = T3J[l], t = T3K[l];
            float R[6], S[6], T[6];
#pragma unroll
            for (int p = 0; p < 6; p++) { R[p]=ML(20+r*6+p); S[p]=ML(20+s*6+p); T[p]=ML(20+t*6+p); }
            float acc = 0.f;
#pragma unroll
            for (int i = 0; i < 3; i++)
#pragma unroll
            for (int j = 0; j < 3; j++)
#pragma unroll
            for (int k = 0; k < 3; k++)
                acc += R[P2[i*3+j]] * S[P2[i*3+k]] * T[P2[j*3+k]];
            v = acc;
            int f = l * NA + a2; int aa = f / 35; dest = aa * OC + 50 + (f - aa*35);
        } else if (cc < 160) {
            int l = cc - 85;
            int p = l / 5, t = l - p*5;
            int r = T2I[p], s = T2J[p];
            float T[6];
#pragma unroll
            for (int q = 0; q < 6; q++) T[q] = ML(20 + t*6 + q);
            float acc = 0.f;
#pragma unroll
            for (int i = 0; i < 3; i++)
#pragma unroll
            for (int j = 0; j < 3; j++)
                acc += ML(5 + r*3 + i) * ML(5 + s*3 + j) * T[P2[i*3+j]];
            v = acc;
            int f = l * NA + a2; int aa = f / 75; dest = aa * OC + 85 + (f - aa*75);
        } else if (cc < 235) {
            int l = cc - 160;
            int p = l / 5, t = l - p*5;
            int r = T2I[p], s = T2J[p];
            float R[10], S[10], T[6];
#pragma unroll
            for (int q = 0; q < 10; q++) { R[q]=ML(50+r*10+q); S[q]=ML(50+s*10+q); }
#pragma unroll
            for (int q = 0; q < 6;  q++) T[q] = ML(20 + t*6 + q);
            float acc = 0.f;
#pragma unroll
            for (int k = 0; k < 3; k++)
#pragma unroll
            for (int l2 = 0; l2 < 3; l2++) {
                float inner = 0.f;
#pragma unroll
                for (int i = 0; i < 3; i++)
#pragma unroll
                for (int j = 0; j < 3; j++)
                    inner += R[P3[(i*3+j)*3+k]] * S[P3[(i*3+j)*3+l2]];
                acc += inner * T[P2[k*3+l2]];
            }
            v = acc;
            int f = l * NA + a2; int aa = f / 75; dest = aa * OC + 160 + (f - aa*75);
        } else {
            int l = cc - 235;
            int r = l / 25; int rem = l - r*25; int s = rem / 5; int t = rem - s*5;
            float R[10], S[6], T1[3];
#pragma unroll
            for (int q = 0; q < 10; q++) R[q] = ML(50 + r*10 + q);
#pragma unroll
            for (int q = 0; q < 6;  q++) S[q] = ML(20 + s*6 + q);
#pragma unroll
            for (int q = 0; q < 3;  q++) T1[q] = ML(5 + t*3 + q);
            float acc = 0.f;
#pragma unroll
            for (int i = 0; i < 3; i++)
#pragma unroll
            for (int j = 0; j < 3; j++)
#pragma unroll
            for (int k = 0; k < 3; k++)
                acc += R[P3[(i*3+j)*3+k]] * S[P2[i*3+j]] * T1[k];
            v = acc;
            int f = l * NA + a2; int aa = f / 125; dest = aa * OC + 235 + (f - aa*125);
        }
        out[dest] = v;
    }
#undef ML
}

extern "C" void kernel_launch(void* const* d_in, const int* in_sizes, int n_in,
                              void* d_out, int out_size, void* d_ws, size_t ws_size,
                              hipStream_t stream) {
    const float* dr_vec = (const float*)d_in[0];
    const int*   Z      = (const int*)d_in[1];
    const int*   nbr    = (const int*)d_in[2];
    const float* coeffs = (const float*)d_in[3];
    float* out = (float*)d_out;

    // fast path workspace: rec[NBK*BCAP*8 floats] | meta[NBK*BCAP u8] | cursor[NBK]
    size_t rec_elems  = (size_t)NBK * BCAP * 8;           // 38.4 MB
    size_t meta_bytes = (size_t)NBK * BCAP;               // 1.2 MB (mult of 4)
    size_t need_fast  = rec_elems * sizeof(float) + meta_bytes + NBK * sizeof(int);

    if (ws_size >= need_fast) {
        float*         rec    = (float*)d_ws;
        unsigned char* meta   = (unsigned char*)(rec + rec_elems);
        int*           cursor = (int*)(meta + meta_bytes);
        hipMemsetAsync(cursor, 0, NBK * sizeof(int), stream);
        edge_record_kernel<<<(NE + 255)/256, 256, 0, stream>>>(dr_vec, Z, nbr, coeffs, cursor, rec, meta);
        accum_contract_kernel<<<NBK, 256, 0, stream>>>(cursor, rec, meta, out);
    } else {
        // round-3 fallback: cursor[NA] | bins[NA*CAPI] | Mu[NA*MUS] (~21.3 MB)
        int*   cursor = (int*)d_ws;
        int*   bins   = cursor + NA;
        float* Mu     = (float*)(bins + (size_t)NA * CAPI);
        hipMemsetAsync(cursor, 0, (size_t)NA * sizeof(int), stream);
        scatter_kernel<<<(NE + 255)/256, 256, 0, stream>>>(nbr, cursor, bins);
        accum_kernel<<<(NA*8 + 255)/256, 256, 0, stream>>>(dr_vec, Z, nbr, coeffs, cursor, bins, Mu);
        contract_kernel<<<(NA + CHUNK - 1)/CHUNK, 256, 0, stream>>>(Mu, out);
    }
}

// Round 7
// 232.550 us; speedup vs baseline: 4.8120x; 4.8120x over previous
//
#include <hip/hip_runtime.h>
#include <math.h>

#define NR 5
#define NB 7
#define NS 119
#define NA 25000
#define NE 1000000
#define OC 360           // output columns per atom
#define MUS 100          // unique moment floats per atom
#define CAPR 104         // per-atom record bin capacity (lambda=40, P(ovf)~1e-13)
#define CAPI 112         // fallback id-bin capacity
#define CHUNK2 32        // atoms per accum_contract block (8 lanes/atom)
#define CHUNK 64         // fallback contract block
#define MPAD 101         // LDS stride: 101 mod 32 = 5, gcd(5,32)=1 -> conflict-free

typedef float fvec4 __attribute__((ext_vector_type(4)));  // NT-store-compatible

// tril index tables (wave-uniform index -> scalar loads)
static constexpr int T2I[15] = {0,1,1,2,2,2,3,3,3,3,4,4,4,4,4};
static constexpr int T2J[15] = {0,0,1,0,1,2,0,1,2,3,0,1,2,3,4};
static constexpr int T3I[35] = {0,1,1,1,2,2,2,2,2,2,3,3,3,3,3,3,3,3,3,3,4,4,4,4,4,4,4,4,4,4,4,4,4,4,4};
static constexpr int T3J[35] = {0,0,1,1,0,1,1,2,2,2,0,1,1,2,2,2,3,3,3,3,0,1,1,2,2,2,3,3,3,3,4,4,4,4,4};
static constexpr int T3K[35] = {0,0,0,1,0,0,1,0,1,2,0,0,1,0,1,2,0,1,2,3,0,0,1,0,1,2,0,1,2,3,0,1,2,3,4};

static constexpr int P2[9]  = {0,1,2, 1,3,4, 2,4,5};
static constexpr int P3[27] = {0,1,4, 1,2,5, 4,5,7,
                               1,2,5, 2,3,6, 5,6,8,
                               4,5,7, 5,6,8, 7,8,9};
static constexpr float W2[6]  = {1.f,2.f,2.f,1.f,2.f,1.f};
static constexpr float W3[10] = {1.f,3.f,3.f,1.f,3.f,6.f,3.f,3.f,3.f,1.f};

// ============================ FAST PATH ==================================
// pass 1: fused edge compute + per-atom record scatter (25000 cursors —
// round-5 showed low-cardinality cursors serialize; per-atom is fine).
__global__ __launch_bounds__(256) void edge_record_kernel(
    const float* __restrict__ dr_vec, const int* __restrict__ Z,
    const int* __restrict__ nbr, const float* __restrict__ coeffs,
    int* __restrict__ cursor, float* __restrict__ binrec)
{
    int e = blockIdx.x * 256 + threadIdx.x;
    if (e >= NE) return;
    float x = dr_vec[3*e+0], y = dr_vec[3*e+1], z = dr_vec[3*e+2];
    int ai = nbr[e];
    int aj = nbr[NE + e];

    float dr = sqrtf(x*x + y*y + z*z);
    if (dr >= 6.0f) return;                 // cutoff==0 -> zero contribution

    // reserve slot early so atomic latency overlaps the math below
    int pos = __hip_atomic_fetch_add(&cursor[aj], 1, __ATOMIC_RELAXED, __HIP_MEMORY_SCOPE_AGENT);

    int Zi = Z[ai], Zj = Z[aj];
    float inv = 1.0f / (dr + 1e-5f);
    float d0 = x*inv, d1 = y*inv, d2 = z*inv;

    const float PI_F = 3.14159265358979323846f;
    const float betta = 49.0f / 36.0f;
    float rad_norm = powf(2.0f * betta / PI_F, 0.75f);   // constant-folded
    float cut = 0.5f*(cosf(PI_F * dr * (1.0f/6.0f)) + 1.0f);
    float scale = cut * 0.3779644730092272272f;          // 1/sqrt(7)

    float basis[NB];
#pragma unroll
    for (int b = 0; b < NB; b++) {
        float t = dr - (float)b;
        basis[b] = rad_norm * expf(-betta * t * t);
    }

    const float* cp = coeffs + ((size_t)(Zi*NS + Zj)) * (NR*NB);
    float rad[NR];
#pragma unroll
    for (int r = 0; r < NR; r++) {
        float s = 0.f;
#pragma unroll
        for (int b = 0; b < NB; b++) s += basis[b] * cp[r*NB + b];
        rad[r] = s * scale;
    }

    if (pos < CAPR) {
        fvec4* rp = (fvec4*)(binrec + ((size_t)aj * CAPR + pos) * 8);
        fvec4 v0 = {rad[0], rad[1], rad[2], rad[3]};
        fvec4 v1 = {rad[4], d0, d1, d2};
        __builtin_nontemporal_store(v0, rp);
        __builtin_nontemporal_store(v1, rp + 1);
    }
}

// pass 2: 32 atoms/block, 8 lanes/atom register accumulation ->
// shuffle-reduce -> LDS tile -> in-place contraction.
__global__ __launch_bounds__(256) void accum_contract_kernel(
    const int* __restrict__ cursor, const float* __restrict__ binrec,
    float* __restrict__ out)
{
    __shared__ float lds[CHUNK2 * MPAD];
    int base = blockIdx.x * CHUNK2;
    int nat  = min(CHUNK2, NA - base);

    int al  = threadIdx.x >> 3;          // local atom 0..31
    int sub = threadIdx.x & 7;
    int a   = base + al;
    int n   = (a < NA) ? min(cursor[a], CAPR) : 0;

    float acc[MUS];
#pragma unroll
    for (int i = 0; i < MUS; i++) acc[i] = 0.f;

    const float* mybin = binrec + (size_t)a * CAPR * 8;
    for (int p = sub; p < n; p += 8) {
        const float4* rp = (const float4*)(mybin + (size_t)p * 8);
        float4 r0 = rp[0], r1 = rp[1];
        float rad[NR] = {r0.x, r0.y, r0.z, r0.w, r1.x};
        float d0 = r1.y, d1 = r1.z, d2 = r1.w;

        float q2[6] = {d0*d0, d1*d0, d2*d0, d1*d1, d2*d1, d2*d2};
        float q3[10] = {d0*q2[0], d1*q2[0], d0*q2[3], d1*q2[3], d2*q2[0],
                        d2*q2[1], d2*q2[3], d0*q2[5], d1*q2[5], d2*q2[5]};

#pragma unroll
        for (int r = 0; r < NR; r++) {
            float rv = rad[r];
            acc[r] += rv;
            acc[5 + r*3 + 0] += rv*d0;
            acc[5 + r*3 + 1] += rv*d1;
            acc[5 + r*3 + 2] += rv*d2;
#pragma unroll
            for (int q = 0; q < 6; q++)  acc[20 + r*6  + q] += rv*q2[q];
#pragma unroll
            for (int q = 0; q < 10; q++) acc[50 + r*10 + q] += rv*q3[q];
        }
    }

    // reduce over 8 sub-lanes (aligned groups within the wave)
#pragma unroll
    for (int i = 0; i < MUS; i++) {
        float v = acc[i];
        v += __shfl_xor(v, 1, 64);
        v += __shfl_xor(v, 2, 64);
        v += __shfl_xor(v, 4, 64);
        if (sub == 0) lds[al * MPAD + i] = v;
    }
    __syncthreads();

    // ---- contract phase: 8 column-streams x 32 atoms, all lanes active ----
    int atom = threadIdx.x & 31;
    int cs   = threadIdx.x >> 5;         // 0..7
    int a2   = base + atom;
    bool valid = (atom < nat);
    int mb = atom * MPAD;

#define ML(o) lds[mb + (o)]

    for (int cc = cs; cc < 360; cc += 8) {
        if (!valid) continue;
        float v; int dest;

        if (cc < 5) {
            v = ML(cc);
            dest = a2 * OC + cc;
        } else if (cc < 20) {
            int l = cc - 5;
            int r = T2I[l], s = T2J[l];
            float acc2 = 0.f;
#pragma unroll
            for (int i = 0; i < 3; i++) acc2 += ML(5 + r*3 + i) * ML(5 + s*3 + i);
            v = acc2;
            int f = l * NA + a2; int aa = f / 15; dest = aa * OC + 5 + (f - aa*15);
        } else if (cc < 35) {
            int l = cc - 20;
            int r = T2I[l], s = T2J[l];
            float acc2 = 0.f;
#pragma unroll
            for (int p = 0; p < 6; p++) acc2 += W2[p] * ML(20 + r*6 + p) * ML(20 + s*6 + p);
            v = acc2;
            int f = l * NA + a2; int aa = f / 15; dest = aa * OC + 20 + (f - aa*15);
        } else if (cc < 50) {
            int l = cc - 35;
            int r = T2I[l], s = T2J[l];
            float acc2 = 0.f;
#pragma unroll
            for (int p = 0; p < 10; p++) acc2 += W3[p] * ML(50 + r*10 + p) * ML(50 + s*10 + p);
            v = acc2;
            int f = l * NA + a2; int aa = f / 15; dest = aa * OC + 35 + (f - aa*15);
        } else if (cc < 85) {
            int l = cc - 50;
            int r = T3I[l], s = T3J[l], t = T3K[l];
            float R[6], S[6], T[6];
#pragma unroll
            for (int p = 0; p < 6; p++) { R[p]=ML(20+r*6+p); S[p]=ML(20+s*6+p); T[p]=ML(20+t*6+p); }
            float acc2 = 0.f;
#pragma unroll
            for (int i = 0; i < 3; i++)
#pragma unroll
            for (int j = 0; j < 3; j++)
#pragma unroll
            for (int k = 0; k < 3; k++)
                acc2 += R[P2[i*3+j]] * S[P2[i*3+k]] * T[P2[j*3+k]];
            v = acc2;
            int f = l * NA + a2; int aa = f / 35; dest = aa * OC + 50 + (f - aa*35);
        } else if (cc < 160) {
            int l = cc - 85;
            int p = l / 5, t = l - p*5;
            int r = T2I[p], s = T2J[p];
            float T[6];
#pragma unroll
            for (int q = 0; q < 6; q++) T[q] = ML(20 + t*6 + q);
            float acc2 = 0.f;
#pragma unroll
            for (int i = 0; i < 3; i++)
#pragma unroll
            for (int j = 0; j < 3; j++)
                acc2 += ML(5 + r*3 + i) * ML(5 + s*3 + j) * T[P2[i*3+j]];
            v = acc2;
            int f = l * NA + a2; int aa = f / 75; dest = aa * OC + 85 + (f - aa*75);
        } else if (cc < 235) {
            int l = cc - 160;
            int p = l / 5, t = l - p*5;
            int r = T2I[p], s = T2J[p];
            float R[10], S[10], T[6];
#pragma unroll
            for (int q = 0; q < 10; q++) { R[q]=ML(50+r*10+q); S[q]=ML(50+s*10+q); }
#pragma unroll
            for (int q = 0; q < 6;  q++) T[q] = ML(20 + t*6 + q);
            float acc2 = 0.f;
#pragma unroll
            for (int k = 0; k < 3; k++)
#pragma unroll
            for (int l2 = 0; l2 < 3; l2++) {
                float inner = 0.f;
#pragma unroll
                for (int i = 0; i < 3; i++)
#pragma unroll
                for (int j = 0; j < 3; j++)
                    inner += R[P3[(i*3+j)*3+k]] * S[P3[(i*3+j)*3+l2]];
                acc2 += inner * T[P2[k*3+l2]];
            }
            v = acc2;
            int f = l * NA + a2; int aa = f / 75; dest = aa * OC + 160 + (f - aa*75);
        } else {
            int l = cc - 235;
            int r = l / 25; int rem = l - r*25; int s = rem / 5; int t = rem - s*5;
            float R[10], S[6], T1[3];
#pragma unroll
            for (int q = 0; q < 10; q++) R[q] = ML(50 + r*10 + q);
#pragma unroll
            for (int q = 0; q < 6;  q++) S[q] = ML(20 + s*6 + q);
#pragma unroll
            for (int q = 0; q < 3;  q++) T1[q] = ML(5 + t*3 + q);
            float acc2 = 0.f;
#pragma unroll
            for (int i = 0; i < 3; i++)
#pragma unroll
            for (int j = 0; j < 3; j++)
#pragma unroll
            for (int k = 0; k < 3; k++)
                acc2 += R[P3[(i*3+j)*3+k]] * S[P2[i*3+j]] * T1[k];
            v = acc2;
            int f = l * NA + a2; int aa = f / 125; dest = aa * OC + 235 + (f - aa*125);
        }
        __builtin_nontemporal_store(v, &out[dest]);
    }
#undef ML
}

// ========================= FALLBACK PATH (round 3) =======================
__global__ __launch_bounds__(256) void scatter_kernel(
    const int* __restrict__ nbr, int* __restrict__ cursor, int* __restrict__ bins)
{
    int e = blockIdx.x * 256 + threadIdx.x;
    if (e >= NE) return;
    int aj = nbr[NE + e];
    int pos = __hip_atomic_fetch_add(&cursor[aj], 1, __ATOMIC_RELAXED, __HIP_MEMORY_SCOPE_AGENT);
    if (pos < CAPI) bins[(size_t)aj * CAPI + pos] = e;
}

__global__ __launch_bounds__(256) void accum_kernel(
    const float* __restrict__ dr_vec, const int* __restrict__ Z,
    const int* __restrict__ nbr, const float* __restrict__ coeffs,
    const int* __restrict__ cursor, const int* __restrict__ bins,
    float* __restrict__ Mu)
{
    __shared__ float red[32 * MUS];
    int t   = blockIdx.x * 256 + threadIdx.x;
    int a   = t >> 3;
    int sub = t & 7;
    int al  = threadIdx.x >> 3;
    int n   = (a < NA) ? min(cursor[a], CAPI) : 0;
    int Zj  = (a < NA) ? Z[a] : 0;

    float acc[MUS];
#pragma unroll
    for (int i = 0; i < MUS; i++) acc[i] = 0.f;

    const int* mybin = bins + (size_t)a * CAPI;
    const float PI_F = 3.14159265358979323846f;
    const float betta = 49.0f / 36.0f;
    float rad_norm = powf(2.0f * betta / PI_F, 0.75f);

    for (int p = sub; p < n; p += 8) {
        int e = mybin[p];
        float x = dr_vec[3*e+0], y = dr_vec[3*e+1], z = dr_vec[3*e+2];
        int Zi = Z[nbr[e]];

        float dr  = sqrtf(x*x + y*y + z*z);
        float inv = 1.0f / (dr + 1e-5f);
        float d0 = x*inv, d1 = y*inv, d2 = z*inv;

        float cut = (dr < 6.0f) ? 0.5f*(cosf(PI_F * dr * (1.0f/6.0f)) + 1.0f) : 0.0f;
        float scale = cut * 0.3779644730092272272f;

        float basis[NB];
#pragma unroll
        for (int b = 0; b < NB; b++) {
            float tt = dr - (float)b;
            basis[b] = rad_norm * expf(-betta * tt * tt);
        }

        const float* cp = coeffs + ((size_t)(Zi*NS + Zj)) * (NR*NB);
        float rad[NR];
#pragma unroll
        for (int r = 0; r < NR; r++) {
            float s = 0.f;
#pragma unroll
            for (int b = 0; b < NB; b++) s += basis[b] * cp[r*NB + b];
            rad[r] = s * scale;
        }

        float q2[6] = {d0*d0, d1*d0, d2*d0, d1*d1, d2*d1, d2*d2};
        float q3[10] = {d0*q2[0], d1*q2[0], d0*q2[3], d1*q2[3], d2*q2[0],
                        d2*q2[1], d2*q2[3], d0*q2[5], d1*q2[5], d2*q2[5]};

#pragma unroll
        for (int r = 0; r < NR; r++) {
            float rv = rad[r];
            acc[r] += rv;
            acc[5 + r*3 + 0] += rv*d0;
            acc[5 + r*3 + 1] += rv*d1;
            acc[5 + r*3 + 2] += rv*d2;
#pragma unroll
            for (int q = 0; q < 6; q++)  acc[20 + r*6  + q] += rv*q2[q];
#pragma unroll
            for (int q = 0; q < 10; q++) acc[50 + r*10 + q] += rv*q3[q];
        }
    }

#pragma unroll
    for (int i = 0; i < MUS; i++) {
        float v = acc[i];
        v += __shfl_xor(v, 1, 64);
        v += __shfl_xor(v, 2, 64);
        v += __shfl_xor(v, 4, 64);
        if (sub == 0) red[al * MUS + i] = v;
    }
    __syncthreads();

    for (int u = threadIdx.x; u < 32 * MUS; u += 256) {
        int ga = blockIdx.x * 32 + u / MUS;
        if (ga < NA) Mu[(size_t)ga * MUS + (u - (u / MUS) * MUS)] = red[u];
    }
}

__global__ __launch_bounds__(256) void contract_kernel(
    const float* __restrict__ Mu, float* __restrict__ out)
{
    __shared__ float lds[CHUNK * MPAD];
    int base = blockIdx.x * CHUNK;
    int nat  = min(CHUNK, NA - base);

    for (int t = threadIdx.x; t < nat * MUS; t += 256) {
        int al = t / MUS, off = t - al * MUS;
        lds[al * MPAD + off] = Mu[(size_t)base * MUS + t];
    }
    __syncthreads();

    int wave = threadIdx.x >> 6, lane = threadIdx.x & 63;
    int a2 = base + lane;
    bool valid = (lane < nat);
    int mb = lane * MPAD;

#define ML(o) lds[mb + (o)]

    for (int cc = wave; cc < 360; cc += 4) {
        if (!valid) continue;
        float v; int dest;

        if (cc < 5) {
            v = ML(cc);
            dest = a2 * OC + cc;
        } else if (cc < 20) {
            int l = cc - 5;
            int r = T2I[l], s = T2J[l];
            float acc = 0.f;
#pragma unroll
            for (int i = 0; i < 3; i++) acc += ML(5 + r*3 + i) * ML(5 + s*3 + i);
            v = acc;
            int f = l * NA + a2; int aa = f / 15; dest = aa * OC + 5 + (f - aa*15);
        } else if (cc < 35) {
            int l = cc - 20;
            int r = T2I[l], s = T2J[l];
            float acc = 0.f;
#pragma unroll
            for (int p = 0; p < 6; p++) acc += W2[p] * ML(20 + r*6 + p) * ML(20 + s*6 + p);
            v = acc;
            int f = l * NA + a2; int aa = f / 15; dest = aa * OC + 20 + (f - aa*15);
        } else if (cc < 50) {
            int l = cc - 35;
            int r = T2I[l], s = T2J[l];
            float acc = 0.f;
#pragma unroll
            for (int p = 0; p < 10; p++) acc += W3[p] * ML(50 + r*10 + p) * ML(50 + s*10 + p);
            v = acc;
            int f = l * NA + a2; int aa = f / 15; dest = aa * OC + 35 + (f - aa*15);
        } else if (cc < 85) {
            int l = cc - 50;
            int r = T3I[l], s = T3J[l], t = T3K[l];
            float R[6], S[6], T[6];
#pragma unroll
            for (int p = 0; p < 6; p++) { R[p]=ML(20+r*6+p); S[p]=ML(20+s*6+p); T[p]=ML(20+t*6+p); }
            float acc = 0.f;
#pragma unroll
            for (int i = 0; i < 3; i++)
#pragma unroll
            for (int j = 0; j < 3; j++)
#pragma unroll
            for (int k = 0; k < 3; k++)
                acc += R[P2[i*3+j]] * S[P2[i*3+k]] * T[P2[j*3+k]];
            v = acc;
            int f = l * NA + a2; int aa = f / 35; dest = aa * OC + 50 + (f - aa*35);
        } else if (cc < 160) {
            int l = cc - 85;
            int p = l / 5, t = l - p*5;
            int r = T2I[p], s = T2J[p];
            float T[6];
#pragma unroll
            for (int q = 0; q < 6; q++) T[q] = ML(20 + t*6 + q);
            float acc = 0.f;
#pragma unroll
            for (int i = 0; i < 3; i++)
#pragma unroll
            for (int j = 0; j < 3; j++)
                acc += ML(5 + r*3 + i) * ML(5 + s*3 + j) * T[P2[i*3+j]];
            v = acc;
            int f = l * NA + a2; int aa = f / 75; dest = aa * OC + 85 + (f - aa*75);
        } else if (cc < 235) {
            int l = cc - 160;
            int p = l / 5, t = l - p*5;
            int r = T2I[p], s = T2J[p];
            float R[10], S[10], T[6];
#pragma unroll
            for (int q = 0; q < 10; q++) { R[q]=ML(50+r*10+q); S[q]=ML(50+s*10+q); }
#pragma unroll
            for (int q = 0; q < 6;  q++) T[q] = ML(20 + t*6 + q);
            float acc = 0.f;
#pragma unroll
            for (int k = 0; k < 3; k++)
#pragma unroll
            for (int l2 = 0; l2 < 3; l2++) {
                float inner = 0.f;
#pragma unroll
                for (int i = 0; i < 3; i++)
#pragma unroll
                for (int j = 0; j < 3; j++)
                    inner += R[P3[(i*3+j)*3+k]] * S[P3[(i*3+j)*3+l2]];
                acc += inner * T[P2[k*3+l2]];
            }
            v = acc;
            int f = l * NA + a2; int aa = f / 75; dest = aa * OC + 160 + (f - aa*75);
        } else {
            int l = cc - 235;
            int r = l / 25; int rem = l - r*25; int s = rem / 5; int t = rem - s*5;
            float R[10], S[6], T1[3];
#pragma unroll
            for (int q = 0; q < 10; q++) R[q] = ML(50 + r*10 + q);
#pragma unroll
            for (int q = 0; q < 6;  q++) S[q] = ML(20 + s*6 + q);
#pragma unroll
            for (int q = 0; q < 3;  q++) T1[q] = ML(5 + t*3 + q);
            float acc = 0.f;
#pragma unroll
            for (int i = 0; i < 3; i++)
#pragma unroll
            for (int j = 0; j < 3; j++)
#pragma unroll
            for (int k = 0; k < 3; k++)
                acc += R[P3[(i*3+j)*3+k]] * S[P2[i*3+j]] * T1[k];
            v = acc;
            int f = l * NA + a2; int aa = f / 125; dest = aa * OC + 235 + (f - aa*125);
        }
        out[dest] = v;
    }
#undef ML
}

extern "C" void kernel_launch(void* const* d_in, const int* in_sizes, int n_in,
                              void* d_out, int out_size, void* d_ws, size_t ws_size,
                              hipStream_t stream) {
    const float* dr_vec = (const float*)d_in[0];
    const int*   Z      = (const int*)d_in[1];
    const int*   nbr    = (const int*)d_in[2];
    const float* coeffs = (const float*)d_in[3];
    float* out = (float*)d_out;

    // fast path workspace: cursor[NA] ints + binrec[NA*CAPR*8] floats (~83.3 MB)
    size_t need_fast = (size_t)NA * sizeof(int) + (size_t)NA * CAPR * 8 * sizeof(float);

    if (ws_size >= need_fast) {
        int*   cursor = (int*)d_ws;
        float* binrec = (float*)(cursor + NA);
        (void)hipMemsetAsync(cursor, 0, (size_t)NA * sizeof(int), stream);
        edge_record_kernel<<<(NE + 255)/256, 256, 0, stream>>>(dr_vec, Z, nbr, coeffs, cursor, binrec);
        accum_contract_kernel<<<(NA + CHUNK2 - 1)/CHUNK2, 256, 0, stream>>>(cursor, binrec, out);
    } else {
        // round-3 fallback: cursor[NA] | bins[NA*CAPI] | Mu[NA*MUS] (~21.3 MB)
        int*   cursor = (int*)d_ws;
        int*   bins   = cursor + NA;
        float* Mu     = (float*)(bins + (size_t)NA * CAPI);
        (void)hipMemsetAsync(cursor, 0, (size_t)NA * sizeof(int), stream);
        scatter_kernel<<<(NE + 255)/256, 256, 0, stream>>>(nbr, cursor, bins);
        accum_kernel<<<(NA*8 + 255)/256, 256, 0, stream>>>(dr_vec, Z, nbr, coeffs, cursor, bins, Mu);
        contract_kernel<<<(NA + CHUNK - 1)/CHUNK, 256, 0, stream>>>(Mu, out);
    }
}